// Round 3
// baseline (1787.853 us; speedup 1.0000x reference)
//
#include <hip/hip_runtime.h>
#include <hip/hip_fp16.h>

typedef _Float16 f16;
typedef _Float16 f16x8 __attribute__((ext_vector_type(8)));
typedef float f32x4 __attribute__((ext_vector_type(4)));

#define B_SZ   4096
#define T_SZ   32
#define VOCAB  10000
#define E_SZ   300
#define H_SZ   300
#define KP     320          // embT row width (10x32)
#define KWP    672          // Wcat padded row width: 1344 B = 21 cache lines (odd -> channel spread)
#define GP     304          // per-gate padded N (19x16)
#define G4     1216         // 4*GP
#define LDA    328          // hbuf row stride f16
#define LDG    1224         // gates row stride f16 (pad +8 to break bank alignment)
#define ROWS   32           // batch rows per block
#define NBLK   (B_SZ/ROWS)  // 128 blocks

__device__ __forceinline__ float sigmoid_f(float x) {
    return 1.f / (1.f + __expf(-x));
}
__device__ __forceinline__ float tanh_f(float x) {
    x = fminf(fmaxf(x, -15.f), 15.f);
    float e = __expf(2.f * x);
    return (e - 1.f) / (e + 1.f);
}

// P0: embed_w f32 [V][300] -> embT f16 [V][320] zero-padded
__global__ void kP0(const float* __restrict__ ew, f16* __restrict__ embT) {
    int v = blockIdx.x, k = threadIdx.x;           // 320 threads
    embT[(size_t)v * KP + k] = (k < E_SZ) ? (f16)ew[(size_t)v * E_SZ + k] : (f16)0.f;
}

// PW: Wcat f16 [1216][672]: cols 0..299 = W_hh row, cols 320..619 = W_ih row, rest 0; bias sum
__global__ void kPW(const float* __restrict__ wih, const float* __restrict__ whh,
                    const float* __restrict__ bih, const float* __restrict__ bhh,
                    f16* __restrict__ Wcat, float* __restrict__ biasp) {
    int np = blockIdx.x;                           // 0..1215
    int k  = threadIdx.x;                          // 0..671
    int g = np / GP, j = np - g * GP;
    bool valid = (j < H_SZ);
    int src = g * H_SZ + j;
    f16 val = (f16)0.f;
    if (valid) {
        if (k < H_SZ)                    val = (f16)whh[(size_t)src * H_SZ + k];
        else if (k >= KP && k < KP + E_SZ) val = (f16)wih[(size_t)src * E_SZ + (k - KP)];
    }
    Wcat[(size_t)np * KWP + k] = val;
    if (k == 0) biasp[np] = valid ? (bih[src] + bhh[src]) : 0.f;
}

// P2: weight-normed classifier W = g * v / ||v||  -> Wc f32 [2][GP]
__global__ void kP2(const float* __restrict__ cls_v, const float* __restrict__ cls_g,
                    float* __restrict__ Wc) {
    int lane = threadIdx.x;                        // 64
    for (int cl = 0; cl < 2; ++cl) {
        float s = 0.f;
        for (int j = lane; j < H_SZ; j += 64) { float v = cls_v[cl * H_SZ + j]; s += v * v; }
        for (int off = 32; off; off >>= 1) s += __shfl_down(s, off);
        float nrm = sqrtf(__shfl(s, 0));
        float scale = cls_g[cl] / nrm;
        for (int j = lane; j < H_SZ; j += 64) Wc[cl * GP + j] = cls_v[cl * H_SZ + j] * scale;
    }
}

// kRf2: fused LSTM recurrence. 128 blocks x 512 thr (8 waves), 32 batch rows/block.
// Wave (mt = w&1, gate = w>>1): 19 nt-tiles, K=640 fused [h|x].
// m-tile wave pairs read identical weight addresses in lockstep -> L1/L2 coalesce.
__global__ __launch_bounds__(512, 2) void kRf2(const int* __restrict__ cap,
                                               const int* __restrict__ cap_len,
                                               const f16* __restrict__ embT,
                                               const f16* __restrict__ Wcat,
                                               const float* __restrict__ biasp,
                                               float* __restrict__ hlast) {
    extern __shared__ __align__(16) char smem[];
    f16* hbuf  = (f16*)smem;                               // [32][LDA]  20992 B
    f16* gates = (f16*)(smem + ROWS * LDA * 2);            // [32][LDG]  78336 B
    int* capv  = (int*)(smem + ROWS * LDA * 2 + ROWS * LDG * 2); // [32][T] 4096 B
    int* lens  = capv + ROWS * T_SZ;                       // [32]       128 B
    int tid = threadIdx.x;
    int b0 = blockIdx.x * ROWS;
    if (tid < ROWS) lens[tid] = cap_len[b0 + tid];
    for (int i = tid; i < ROWS * T_SZ; i += 512) capv[i] = cap[(size_t)b0 * T_SZ + i];
    for (int i = tid; i < ROWS * LDA; i += 512) hbuf[i] = (f16)0.f;  // pads stay 0 forever
    __syncthreads();
    int wave = tid >> 6, lane = tid & 63;
    int c = lane & 15, q = lane >> 4;
    int mt = wave & 1, gate = wave >> 1;
    const f16* Wg = Wcat + (size_t)(gate * GP) * KWP;
    const f16* hrow = hbuf + (mt * 16 + c) * LDA + q * 8;
    const int* crow = capv + (mt * 16 + c) * T_SZ;
    float creg[20];
#pragma unroll
    for (int i = 0; i < 20; ++i) creg[i] = 0.f;
    for (int t = 0; t < T_SZ; ++t) {
        // --- phase 1: gates[mt-tile][gate cols] = [h|x] @ Wcat^T + bias ---
        f16x8 afr[10], afx[10];
        int v = crow[t];
        const f16* xrow = embT + (size_t)v * KP + q * 8;
#pragma unroll
        for (int k = 0; k < 10; ++k) {
            afr[k] = *(const f16x8*)(hrow + k * 32);
            afx[k] = *(const f16x8*)(xrow + k * 32);
        }
        for (int nt = 0; nt < 19; ++nt) {
            int ncol = gate * GP + nt * 16 + c;
            float bia = biasp[ncol];
            f32x4 acch = {bia, bia, bia, bia};
            f32x4 accx = {0.f, 0.f, 0.f, 0.f};
            const f16* wrow = Wg + (size_t)(nt * 16 + c) * KWP + q * 8;
#pragma unroll
            for (int k = 0; k < 10; ++k)
                acch = __builtin_amdgcn_mfma_f32_16x16x32_f16(
                    afr[k], *(const f16x8*)(wrow + k * 32), acch, 0, 0, 0);
#pragma unroll
            for (int k = 0; k < 10; ++k)
                accx = __builtin_amdgcn_mfma_f32_16x16x32_f16(
                    afx[k], *(const f16x8*)(wrow + KP + k * 32), accx, 0, 0, 0);
#pragma unroll
            for (int r = 0; r < 4; ++r)
                gates[(mt * 16 + q * 4 + r) * LDG + ncol] = (f16)(acch[r] + accx[r]);
        }
        __syncthreads();
        // --- phase 2: elementwise cell update; (m,j) slots fixed over t -> c in regs ---
#pragma unroll
        for (int it = 0; it < 20; ++it) {
            int idx = tid + it * 512;              // 0..10239 = 32*320
            int m = idx / 320, j = idx - m * 320;
            if (j < H_SZ) {
                const f16* gr = gates + m * LDG;
                float gi = (float)gr[j];
                float gf = (float)gr[GP + j];
                float gg = (float)gr[2 * GP + j];
                float go = (float)gr[3 * GP + j];
                float ii = sigmoid_f(gi);
                float ff = sigmoid_f(gf);
                float gt = tanh_f(gg);
                float oo = sigmoid_f(go);
                float cn = ff * creg[it] + ii * gt;
                creg[it] = cn;
                float hh = oo * tanh_f(cn);
                hbuf[m * LDA + j] = (f16)hh;
                if (t == lens[m] - 1) hlast[(size_t)(b0 + m) * GP + j] = hh;
            }
        }
        __syncthreads();
    }
}

// kC: out[row][cl] = hlast[row] . Wc[cl] + cls_b[cl]
__global__ void kC(const float* __restrict__ hlast, const float* __restrict__ Wc,
                   const float* __restrict__ cls_b, float* __restrict__ out) {
    int row = blockIdx.x, lane = threadIdx.x;      // 64 threads
    const float* h = hlast + (size_t)row * GP;
    float s0 = 0.f, s1 = 0.f;
    for (int j = lane; j < H_SZ; j += 64) {
        float hv = h[j];
        s0 += hv * Wc[j];
        s1 += hv * Wc[GP + j];
    }
    for (int off = 32; off; off >>= 1) {
        s0 += __shfl_down(s0, off);
        s1 += __shfl_down(s1, off);
    }
    if (lane == 0) {
        out[row * 2 + 0] = s0 + cls_b[0];
        out[row * 2 + 1] = s1 + cls_b[1];
    }
}

extern "C" void kernel_launch(void* const* d_in, const int* in_sizes, int n_in,
                              void* d_out, int out_size, void* d_ws, size_t ws_size,
                              hipStream_t stream) {
    const int*   cap     = (const int*)d_in[0];
    const int*   cap_len = (const int*)d_in[1];
    const float* embed_w = (const float*)d_in[2];
    const float* W_ih    = (const float*)d_in[3];
    const float* W_hh    = (const float*)d_in[4];
    const float* b_ih    = (const float*)d_in[5];
    const float* b_hh    = (const float*)d_in[6];
    const float* cls_v   = (const float*)d_in[7];
    const float* cls_g   = (const float*)d_in[8];
    const float* cls_b   = (const float*)d_in[9];
    float* out = (float*)d_out;

    char* w = (char*)d_ws;
    size_t off = 0;
    auto alloc = [&](size_t bytes) -> void* {
        void* p = w + off;
        off += (bytes + 255) & ~(size_t)255;
        return p;
    };
    f16*   embT  = (f16*)alloc((size_t)VOCAB * KP * sizeof(f16));    // 6.4 MB
    f16*   Wcat  = (f16*)alloc((size_t)G4 * KWP * sizeof(f16));      // 1.63 MB
    float* biasp = (float*)alloc((size_t)G4 * sizeof(float));
    float* Wc    = (float*)alloc((size_t)2 * GP * sizeof(float));
    float* hlast = (float*)alloc((size_t)B_SZ * GP * sizeof(float)); // 5.0 MB

    // dynamic LDS: 103,552 B > 64 KB default -> raise the cap (host config op,
    // idempotent, not a stream operation -> graph-capture safe)
    static const int smem_bytes = ROWS * LDA * 2 + ROWS * LDG * 2 + ROWS * T_SZ * 4 + ROWS * 4;
    (void)hipFuncSetAttribute((const void*)kRf2,
                              hipFuncAttributeMaxDynamicSharedMemorySize, smem_bytes);

    kP0<<<VOCAB, KP, 0, stream>>>(embed_w, embT);
    kPW<<<G4, KWP, 0, stream>>>(W_ih, W_hh, b_ih, b_hh, Wcat, biasp);
    kP2<<<1, 64, 0, stream>>>(cls_v, cls_g, Wc);
    kRf2<<<NBLK, 512, smem_bytes, stream>>>(cap, cap_len, embT, Wcat, biasp, hlast);
    kC<<<B_SZ, 64, 0, stream>>>(hlast, Wc, cls_b, out);
}

// Round 4
// 1220.701 us; speedup vs baseline: 1.4646x; 1.4646x over previous
//
#include <hip/hip_runtime.h>
#include <hip/hip_fp16.h>

typedef _Float16 f16;
typedef _Float16 f16x8 __attribute__((ext_vector_type(8)));
typedef float f32x4 __attribute__((ext_vector_type(4)));

#define B_SZ   4096
#define T_SZ   32
#define VOCAB  10000
#define E_SZ   300
#define H_SZ   300
#define KP     320          // embT row width (10x32)
#define GP     304          // per-gate padded N (19x16)
#define G4     1216         // 4*GP
#define LDA    328          // hbuf row stride f16
#define LDG    1224         // gates row stride f16
#define ROWS   32           // batch rows per block
#define NBLK   (B_SZ/ROWS)  // 128 blocks

__device__ __forceinline__ float sigmoid_f(float x) {
    return 1.f / (1.f + __expf(-x));
}
__device__ __forceinline__ float tanh_f(float x) {
    x = fminf(fmaxf(x, -15.f), 15.f);
    float e = __expf(2.f * x);
    return (e - 1.f) / (e + 1.f);
}

// P0: embed_w f32 [V][300] -> embT f16 [V][320] zero-padded
__global__ void kP0(const float* __restrict__ ew, f16* __restrict__ embT) {
    int v = blockIdx.x, k = threadIdx.x;           // 320 threads
    embT[(size_t)v * KP + k] = (k < E_SZ) ? (f16)ew[(size_t)v * E_SZ + k] : (f16)0.f;
}

// kPW2: pack weights into MFMA-B-fragment order, coalesced.
// Wpk block (gate,nt,k) = 1024 B; lane (c,q) holds W[n=gate*300+nt*16+c][kk=k*32+q*8..+7]
// where kk<320 -> W_hh col kk, kk>=320 -> W_ih col kk-320 (zero-padded).
__global__ void kPW2(const float* __restrict__ wih, const float* __restrict__ whh,
                     const float* __restrict__ bih, const float* __restrict__ bhh,
                     f16* __restrict__ Wpk, float* __restrict__ biasp) {
    int bid = blockIdx.x;                          // 0..1519 = (gate*19+nt)*20+k
    int lane = threadIdx.x;                        // 64
    int k = bid % 20, ntg = bid / 20;
    int nt = ntg % 19, gate = ntg / 19;
    int c = lane & 15, q = lane >> 4;
    int j = nt * 16 + c;                           // 0..303
    int src = gate * H_SZ + j;
    f16 vals[8];
#pragma unroll
    for (int jj = 0; jj < 8; ++jj) {
        int kk = k * 32 + q * 8 + jj;
        float v = 0.f;
        if (j < H_SZ) {
            if (kk < KP) { if (kk < H_SZ) v = whh[(size_t)src * H_SZ + kk]; }
            else { int kx = kk - KP; if (kx < E_SZ) v = wih[(size_t)src * E_SZ + kx]; }
        }
        vals[jj] = (f16)v;
    }
    *(f16x8*)(Wpk + ((size_t)bid * 64 + lane) * 8) = *(const f16x8*)vals;
    if (k == 0 && q == 0)
        biasp[gate * GP + j] = (j < H_SZ) ? (bih[src] + bhh[src]) : 0.f;
}

// P2: weight-normed classifier W = g * v / ||v||  -> Wc f32 [2][GP]
__global__ void kP2(const float* __restrict__ cls_v, const float* __restrict__ cls_g,
                    float* __restrict__ Wc) {
    int lane = threadIdx.x;                        // 64
    for (int cl = 0; cl < 2; ++cl) {
        float s = 0.f;
        for (int j = lane; j < H_SZ; j += 64) { float v = cls_v[cl * H_SZ + j]; s += v * v; }
        for (int off = 32; off; off >>= 1) s += __shfl_down(s, off);
        float nrm = sqrtf(__shfl(s, 0));
        float scale = cls_g[cl] / nrm;
        for (int j = lane; j < H_SZ; j += 64) Wc[cl * GP + j] = cls_v[cl * H_SZ + j] * scale;
    }
}

// kR3: fused LSTM recurrence. 128 blocks x 512 thr (8 waves), 32 rows/block.
// Wave (gate = w>>1, nhalf = w&1) computes its gate's n-slice for BOTH 16-row
// m-tiles (B-frags register-reused x2). Weights read as a linear packed stream.
__global__ __launch_bounds__(512, 2) void kR3(const int* __restrict__ cap,
                                              const int* __restrict__ cap_len,
                                              const f16* __restrict__ embT,
                                              const f16* __restrict__ Wpk,
                                              const float* __restrict__ biasp,
                                              float* __restrict__ hlast) {
    extern __shared__ __align__(16) char smem[];
    f16*   hbuf  = (f16*)smem;                             // 32*LDA*2  = 20992
    f16*   gates = (f16*)(smem + 20992);                   // 32*LDG*2  = 78336
    float* cbuf  = (float*)(smem + 20992 + 78336);         // 10240*4   = 40960
    float* biasL = (float*)(smem + 20992 + 78336 + 40960); // 1216*4    = 4864
    int*   capv  = (int*)(smem + 20992 + 78336 + 40960 + 4864); // 1024*4 = 4096
    int*   lens  = capv + ROWS * T_SZ;                     // 32*4 = 128
    int tid = threadIdx.x;
    int b0 = blockIdx.x * ROWS;
    if (tid < ROWS) lens[tid] = cap_len[b0 + tid];
    for (int i = tid; i < ROWS * T_SZ; i += 512) capv[i] = cap[(size_t)b0 * T_SZ + i];
    for (int i = tid; i < ROWS * LDA; i += 512) hbuf[i] = (f16)0.f;  // pads stay 0
    for (int i = tid; i < ROWS * 320; i += 512) cbuf[i] = 0.f;
    for (int i = tid; i < G4; i += 512) biasL[i] = biasp[i];
    __syncthreads();
    int wave = tid >> 6, lane = tid & 63;
    int c = lane & 15, q = lane >> 4;
    int gate = wave >> 1, nh = wave & 1;
    int nt0 = nh * 10, ntN = nh ? 9 : 10;
    // this wave's packed weight stream start (lane-resolved)
    const f16* wp0 = Wpk + ((size_t)((gate * 19 + nt0) * 20) * 64 + lane) * 8;

    for (int t = 0; t < T_SZ; ++t) {
        // --- phase 1: gate preacts for 2 m-tiles, K=640 fused [h|x] ---
        f16x8 afr[2][10], afx[2][10];
#pragma unroll
        for (int mt = 0; mt < 2; ++mt) {
            const f16* hrow = hbuf + (mt * 16 + c) * LDA + q * 8;
            int v = capv[(mt * 16 + c) * T_SZ + t];
            const f16* xrow = embT + (size_t)v * KP + q * 8;
#pragma unroll
            for (int k = 0; k < 10; ++k) {
                afr[mt][k] = *(const f16x8*)(hrow + k * 32);
                afx[mt][k] = *(const f16x8*)(xrow + k * 32);
            }
        }
        const f16* wp = wp0;
        for (int nt = nt0; nt < nt0 + ntN; ++nt) {
            int ncol = gate * GP + nt * 16 + c;
            float bia = biasL[ncol];
            f32x4 acc0 = {bia, bia, bia, bia};
            f32x4 acc1 = {bia, bia, bia, bia};
            // h-part: load 10 frags, 20 MFMA (2 indep chains)
#pragma unroll
            for (int k = 0; k < 10; ++k) {
                f16x8 bf = *(const f16x8*)(wp + (size_t)k * 512);
                acc0 = __builtin_amdgcn_mfma_f32_16x16x32_f16(afr[0][k], bf, acc0, 0, 0, 0);
                acc1 = __builtin_amdgcn_mfma_f32_16x16x32_f16(afr[1][k], bf, acc1, 0, 0, 0);
            }
            // x-part
#pragma unroll
            for (int k = 0; k < 10; ++k) {
                f16x8 bf = *(const f16x8*)(wp + (size_t)(10 + k) * 512);
                acc0 = __builtin_amdgcn_mfma_f32_16x16x32_f16(afx[0][k], bf, acc0, 0, 0, 0);
                acc1 = __builtin_amdgcn_mfma_f32_16x16x32_f16(afx[1][k], bf, acc1, 0, 0, 0);
            }
#pragma unroll
            for (int r = 0; r < 4; ++r) {
                gates[(q * 4 + r) * LDG + ncol]        = (f16)acc0[r];
                gates[(16 + q * 4 + r) * LDG + ncol]   = (f16)acc1[r];
            }
            wp += 20 * 512;
        }
        __syncthreads();
        // --- phase 2: elementwise cell update; c-state in LDS (fixed idx map) ---
#pragma unroll
        for (int it = 0; it < 20; ++it) {
            int idx = tid + it * 512;              // 0..10239 = 32*320
            int m = idx / 320, j = idx - m * 320;
            if (j < H_SZ) {
                const f16* gr = gates + m * LDG;
                float gi = (float)gr[j];
                float gf = (float)gr[GP + j];
                float gg = (float)gr[2 * GP + j];
                float go = (float)gr[3 * GP + j];
                float ii = sigmoid_f(gi);
                float ff = sigmoid_f(gf);
                float gt = tanh_f(gg);
                float oo = sigmoid_f(go);
                float cn = ff * cbuf[idx] + ii * gt;
                cbuf[idx] = cn;
                float hh = oo * tanh_f(cn);
                hbuf[m * LDA + j] = (f16)hh;
                if (t == lens[m] - 1) hlast[(size_t)(b0 + m) * GP + j] = hh;
            }
        }
        __syncthreads();
    }
}

// kC: out[row][cl] = hlast[row] . Wc[cl] + cls_b[cl]
__global__ void kC(const float* __restrict__ hlast, const float* __restrict__ Wc,
                   const float* __restrict__ cls_b, float* __restrict__ out) {
    int row = blockIdx.x, lane = threadIdx.x;      // 64 threads
    const float* h = hlast + (size_t)row * GP;
    float s0 = 0.f, s1 = 0.f;
    for (int j = lane; j < H_SZ; j += 64) {
        float hv = h[j];
        s0 += hv * Wc[j];
        s1 += hv * Wc[GP + j];
    }
    for (int off = 32; off; off >>= 1) {
        s0 += __shfl_down(s0, off);
        s1 += __shfl_down(s1, off);
    }
    if (lane == 0) {
        out[row * 2 + 0] = s0 + cls_b[0];
        out[row * 2 + 1] = s1 + cls_b[1];
    }
}

extern "C" void kernel_launch(void* const* d_in, const int* in_sizes, int n_in,
                              void* d_out, int out_size, void* d_ws, size_t ws_size,
                              hipStream_t stream) {
    const int*   cap     = (const int*)d_in[0];
    const int*   cap_len = (const int*)d_in[1];
    const float* embed_w = (const float*)d_in[2];
    const float* W_ih    = (const float*)d_in[3];
    const float* W_hh    = (const float*)d_in[4];
    const float* b_ih    = (const float*)d_in[5];
    const float* b_hh    = (const float*)d_in[6];
    const float* cls_v   = (const float*)d_in[7];
    const float* cls_g   = (const float*)d_in[8];
    const float* cls_b   = (const float*)d_in[9];
    float* out = (float*)d_out;

    char* w = (char*)d_ws;
    size_t off = 0;
    auto alloc = [&](size_t bytes) -> void* {
        void* p = w + off;
        off += (bytes + 255) & ~(size_t)255;
        return p;
    };
    f16*   embT  = (f16*)alloc((size_t)VOCAB * KP * sizeof(f16));      // 6.4 MB
    f16*   Wpk   = (f16*)alloc((size_t)1520 * 64 * 8 * sizeof(f16));   // 1.56 MB
    float* biasp = (float*)alloc((size_t)G4 * sizeof(float));
    float* Wc    = (float*)alloc((size_t)2 * GP * sizeof(float));
    float* hlast = (float*)alloc((size_t)B_SZ * GP * sizeof(float));   // 5.0 MB

    // dynamic LDS: 149,376 B (< 160 KiB/CU). Host-side config op, capture-safe.
    static const int smem_bytes = 20992 + 78336 + 40960 + 4864 + 4096 + 128;
    (void)hipFuncSetAttribute((const void*)kR3,
                              hipFuncAttributeMaxDynamicSharedMemorySize, smem_bytes);

    kP0<<<VOCAB, KP, 0, stream>>>(embed_w, embT);
    kPW2<<<1520, 64, 0, stream>>>(W_ih, W_hh, b_ih, b_hh, Wpk, biasp);
    kP2<<<1, 64, 0, stream>>>(cls_v, cls_g, Wc);
    kR3<<<NBLK, 512, smem_bytes, stream>>>(cap, cap_len, embT, Wpk, biasp, hlast);
    kC<<<B_SZ, 64, 0, stream>>>(hlast, Wc, cls_b, out);
}

// Round 5
// 656.449 us; speedup vs baseline: 2.7235x; 1.8596x over previous
//
#include <hip/hip_runtime.h>
#include <hip/hip_fp16.h>

typedef _Float16 f16;
typedef _Float16 f16x8 __attribute__((ext_vector_type(8)));
typedef float f32x4 __attribute__((ext_vector_type(4)));

#define B_SZ   4096
#define T_SZ   32
#define VOCAB  10000
#define E_SZ   300
#define H_SZ   300
#define KP     320          // embT row width (10x32)
#define GP     304          // per-gate padded N (19x16)
#define G4     1216         // 4*GP
#define LDA    328          // hbuf/xbuf row stride f16
#define LDG    1224         // gates row stride f16
#define ROWS   16           // batch rows per block
#define NBLK   (B_SZ/ROWS)  // 256 blocks -> 1 per CU

__device__ __forceinline__ float sigmoid_f(float x) {
    return 1.f / (1.f + __expf(-x));
}
__device__ __forceinline__ float tanh_f(float x) {
    x = fminf(fmaxf(x, -15.f), 15.f);
    float e = __expf(2.f * x);
    return (e - 1.f) / (e + 1.f);
}

// P0: embed_w f32 [V][300] -> embT f16 [V][320] zero-padded
__global__ void kP0(const float* __restrict__ ew, f16* __restrict__ embT) {
    int v = blockIdx.x, k = threadIdx.x;           // 320 threads
    embT[(size_t)v * KP + k] = (k < E_SZ) ? (f16)ew[(size_t)v * E_SZ + k] : (f16)0.f;
}

// kPW2: pack weights into MFMA-B-fragment order, coalesced.
// Wpk block (gate,nt,k) = 1024 B; lane (c,q) holds W[n=gate*300+nt*16+c][kk=k*32+q*8..+7]
// kk<320 -> W_hh col kk, kk>=320 -> W_ih col kk-320 (zero-padded).
__global__ void kPW2(const float* __restrict__ wih, const float* __restrict__ whh,
                     const float* __restrict__ bih, const float* __restrict__ bhh,
                     f16* __restrict__ Wpk, float* __restrict__ biasp) {
    int bid = blockIdx.x;                          // 0..1519 = (gate*19+nt)*20+k
    int lane = threadIdx.x;                        // 64
    int k = bid % 20, ntg = bid / 20;
    int nt = ntg % 19, gate = ntg / 19;
    int c = lane & 15, q = lane >> 4;
    int j = nt * 16 + c;                           // 0..303
    int src = gate * H_SZ + j;
    f16 vals[8];
#pragma unroll
    for (int jj = 0; jj < 8; ++jj) {
        int kk = k * 32 + q * 8 + jj;
        float v = 0.f;
        if (j < H_SZ) {
            if (kk < KP) { if (kk < H_SZ) v = whh[(size_t)src * H_SZ + kk]; }
            else { int kx = kk - KP; if (kx < E_SZ) v = wih[(size_t)src * E_SZ + kx]; }
        }
        vals[jj] = (f16)v;
    }
    *(f16x8*)(Wpk + ((size_t)bid * 64 + lane) * 8) = *(const f16x8*)vals;
    if (k == 0 && q == 0)
        biasp[gate * GP + j] = (j < H_SZ) ? (bih[src] + bhh[src]) : 0.f;
}

// P2: weight-normed classifier W = g * v / ||v||  -> Wc f32 [2][GP]
__global__ void kP2(const float* __restrict__ cls_v, const float* __restrict__ cls_g,
                    float* __restrict__ Wc) {
    int lane = threadIdx.x;                        // 64
    for (int cl = 0; cl < 2; ++cl) {
        float s = 0.f;
        for (int j = lane; j < H_SZ; j += 64) { float v = cls_v[cl * H_SZ + j]; s += v * v; }
        for (int off = 32; off; off >>= 1) s += __shfl_down(s, off);
        float nrm = sqrtf(__shfl(s, 0));
        float scale = cls_g[cl] / nrm;
        for (int j = lane; j < H_SZ; j += 64) Wc[cl * GP + j] = cls_v[cl * H_SZ + j] * scale;
    }
}

// kR4: fused LSTM recurrence. 256 blocks x 1024 thr (16 waves), 16 rows/block.
// Wave (gate = w>>2, q4 = w&3): n-quarter of one gate, TM=1 (fits 128 VGPRs).
// x-rows staged into LDS during previous step's phase 2.
__global__ __launch_bounds__(1024, 4) void kR4(const int* __restrict__ cap,
                                               const int* __restrict__ cap_len,
                                               const f16* __restrict__ embT,
                                               const f16* __restrict__ Wpk,
                                               const float* __restrict__ biasp,
                                               float* __restrict__ hlast) {
    extern __shared__ __align__(16) char smem[];
    f16*   hbuf  = (f16*)smem;                              // 16*LDA*2 = 10496
    f16*   xbuf  = (f16*)(smem + 10496);                    // 10496
    f16*   gates = (f16*)(smem + 20992);                    // 16*LDG*2 = 39168
    float* cbuf  = (float*)(smem + 20992 + 39168);          // 16*320*4 = 20480
    float* biasL = (float*)(smem + 20992 + 39168 + 20480);  // 4864
    int*   capv  = (int*)(smem + 20992 + 39168 + 20480 + 4864); // 16*32*4 = 2048
    int*   lens  = capv + ROWS * T_SZ;                      // 64
    int tid = threadIdx.x;
    int b0 = blockIdx.x * ROWS;
    if (tid < ROWS) lens[tid] = cap_len[b0 + tid];
    for (int i = tid; i < ROWS * T_SZ; i += 1024) capv[i] = cap[(size_t)b0 * T_SZ + i];
    for (int i = tid; i < ROWS * LDA; i += 1024) hbuf[i] = (f16)0.f;  // pads stay 0
    for (int i = tid; i < ROWS * 320; i += 1024) cbuf[i] = 0.f;
    for (int i = tid; i < G4; i += 1024) biasL[i] = biasp[i];
    __syncthreads();
    // stage x for t=0 (xbuf pads: k>=300 of embT rows are already 0; cols up to 320 loaded)
    if (tid < ROWS * 40) {
        int m = tid / 40, c8 = tid - m * 40;
        int v = capv[m * T_SZ + 0];
        *(f16x8*)(xbuf + m * LDA + c8 * 8) = *(const f16x8*)(embT + (size_t)v * KP + c8 * 8);
    }
    __syncthreads();
    int wave = tid >> 6, lane = tid & 63;
    int c = lane & 15, q = lane >> 4;
    int gate = wave >> 2, q4 = wave & 3;
    int nt0 = q4 * 5, cnt = (q4 == 3) ? 4 : 5;     // 19 = 5+5+5+4
    const f16* wp0 = Wpk + ((size_t)((gate * 19 + nt0) * 20) * 64 + lane) * 8;

    for (int t = 0; t < T_SZ; ++t) {
        // --- phase 1: gate preacts, K=640 fused [h|x], TM=1 ---
        f16x8 afr[10], afx[10];
        {
            const f16* hrow = hbuf + c * LDA + q * 8;
            const f16* xrow = xbuf + c * LDA + q * 8;
#pragma unroll
            for (int k = 0; k < 10; ++k) {
                afr[k] = *(const f16x8*)(hrow + k * 32);
                afx[k] = *(const f16x8*)(xrow + k * 32);
            }
        }
        const f16* wp = wp0;
        for (int nt = 0; nt < cnt; ++nt) {
            int ncol = gate * GP + (nt0 + nt) * 16 + c;
            float bia = biasL[ncol];
            f32x4 acc = {bia, bia, bia, bia};
#pragma unroll
            for (int k = 0; k < 10; ++k) {
                f16x8 bf = *(const f16x8*)(wp + (size_t)k * 512);
                acc = __builtin_amdgcn_mfma_f32_16x16x32_f16(afr[k], bf, acc, 0, 0, 0);
            }
#pragma unroll
            for (int k = 0; k < 10; ++k) {
                f16x8 bf = *(const f16x8*)(wp + (size_t)(10 + k) * 512);
                acc = __builtin_amdgcn_mfma_f32_16x16x32_f16(afx[k], bf, acc, 0, 0, 0);
            }
#pragma unroll
            for (int r = 0; r < 4; ++r)
                gates[(q * 4 + r) * LDG + ncol] = (f16)acc[r];
            wp += 20 * 512;
        }
        __syncthreads();
        // --- phase 2: elementwise cell update + stage x(t+1) ---
        int tp1 = t + 1;
        if (tp1 < T_SZ && tid < ROWS * 40) {
            int m = tid / 40, c8 = tid - m * 40;
            int v = capv[m * T_SZ + tp1];
            *(f16x8*)(xbuf + m * LDA + c8 * 8) = *(const f16x8*)(embT + (size_t)v * KP + c8 * 8);
        }
#pragma unroll
        for (int it = 0; it < 5; ++it) {
            int idx = tid + it * 1024;             // 0..5119 = 16*320
            int m = idx / 320, j = idx - m * 320;
            if (j < H_SZ) {
                const f16* gr = gates + m * LDG;
                float gi = (float)gr[j];
                float gf = (float)gr[GP + j];
                float gg = (float)gr[2 * GP + j];
                float go = (float)gr[3 * GP + j];
                float ii = sigmoid_f(gi);
                float ff = sigmoid_f(gf);
                float gt = tanh_f(gg);
                float oo = sigmoid_f(go);
                float cn = ff * cbuf[idx] + ii * gt;
                cbuf[idx] = cn;
                float hh = oo * tanh_f(cn);
                hbuf[m * LDA + j] = (f16)hh;
                if (t == lens[m] - 1) hlast[(size_t)(b0 + m) * GP + j] = hh;
            }
        }
        __syncthreads();
    }
}

// kC: out[row][cl] = hlast[row] . Wc[cl] + cls_b[cl]
__global__ void kC(const float* __restrict__ hlast, const float* __restrict__ Wc,
                   const float* __restrict__ cls_b, float* __restrict__ out) {
    int row = blockIdx.x, lane = threadIdx.x;      // 64 threads
    const float* h = hlast + (size_t)row * GP;
    float s0 = 0.f, s1 = 0.f;
    for (int j = lane; j < H_SZ; j += 64) {
        float hv = h[j];
        s0 += hv * Wc[j];
        s1 += hv * Wc[GP + j];
    }
    for (int off = 32; off; off >>= 1) {
        s0 += __shfl_down(s0, off);
        s1 += __shfl_down(s1, off);
    }
    if (lane == 0) {
        out[row * 2 + 0] = s0 + cls_b[0];
        out[row * 2 + 1] = s1 + cls_b[1];
    }
}

extern "C" void kernel_launch(void* const* d_in, const int* in_sizes, int n_in,
                              void* d_out, int out_size, void* d_ws, size_t ws_size,
                              hipStream_t stream) {
    const int*   cap     = (const int*)d_in[0];
    const int*   cap_len = (const int*)d_in[1];
    const float* embed_w = (const float*)d_in[2];
    const float* W_ih    = (const float*)d_in[3];
    const float* W_hh    = (const float*)d_in[4];
    const float* b_ih    = (const float*)d_in[5];
    const float* b_hh    = (const float*)d_in[6];
    const float* cls_v   = (const float*)d_in[7];
    const float* cls_g   = (const float*)d_in[8];
    const float* cls_b   = (const float*)d_in[9];
    float* out = (float*)d_out;

    char* w = (char*)d_ws;
    size_t off = 0;
    auto alloc = [&](size_t bytes) -> void* {
        void* p = w + off;
        off += (bytes + 255) & ~(size_t)255;
        return p;
    };
    f16*   embT  = (f16*)alloc((size_t)VOCAB * KP * sizeof(f16));      // 6.4 MB
    f16*   Wpk   = (f16*)alloc((size_t)1520 * 64 * 8 * sizeof(f16));   // 1.56 MB
    float* biasp = (float*)alloc((size_t)G4 * sizeof(float));
    float* Wc    = (float*)alloc((size_t)2 * GP * sizeof(float));
    float* hlast = (float*)alloc((size_t)B_SZ * GP * sizeof(float));   // 5.0 MB

    // dynamic LDS: 87,616 B. Host-side config op, capture-safe.
    static const int smem_bytes = 20992 + 39168 + 20480 + 4864 + 2048 + 64;
    (void)hipFuncSetAttribute((const void*)kR4,
                              hipFuncAttributeMaxDynamicSharedMemorySize, smem_bytes);

    kP0<<<VOCAB, KP, 0, stream>>>(embed_w, embT);
    kPW2<<<1520, 64, 0, stream>>>(W_ih, W_hh, b_ih, b_hh, Wpk, biasp);
    kP2<<<1, 64, 0, stream>>>(cls_v, cls_g, Wc);
    kR4<<<NBLK, 1024, smem_bytes, stream>>>(cap, cap_len, embT, Wpk, biasp, hlast);
    kC<<<B_SZ, 64, 0, stream>>>(hlast, Wc, cls_b, out);
}